// Round 9
// baseline (133.406 us; speedup 1.0000x reference)
//
#include <hip/hip_runtime.h>

// segment_sum via fixed-stride bucketing + gather, exact overflow fold.
// E = 1M edges, D = 64 f32 features, N = 100K nodes.
// R8 micros on R7 base: int4 bucket-row loads, grid-stride gather (2048
// blocks), 512-thread scatter. No NT (R3), no cooperative fusion (R6).
//
// ws ints: cursor[N] | ovf_cnt(+3 pad) | ovf[2*OVF_CAP] | bucket[N*CAP]

typedef float f4 __attribute__((ext_vector_type(4)));

#define FEAT 64
#define CAP 32            // one 128B line per node row (avg deg 10)
#define OVF_CAP (1 << 20)

__global__ void __launch_bounds__(512)
scatter_kernel(const int* __restrict__ tgt, int* __restrict__ cursor,
               int* __restrict__ bucket, int* __restrict__ ovf_cnt,
               int* __restrict__ ovf, int E) {
    int i = blockIdx.x * 512 + threadIdx.x;
    if (i >= E) return;
    int t = tgt[i];
    int pos = atomicAdd(&cursor[t], 1);
    if (pos < CAP) {
        bucket[t * CAP + pos] = i;    // plain store: L2 coalesces the region
    } else {                          // exact fallback, expected never
        int q = atomicAdd(ovf_cnt, 1);
        if (q < OVF_CAP) { ovf[2 * q] = t; ovf[2 * q + 1] = i; }
    }
}

// 16-lane group per node; lane = float4 slot; grid-stride over nodes
__global__ void __launch_bounds__(256)
gather_kernel(const f4* __restrict__ mj4, const int* __restrict__ cursor,
              const int4* __restrict__ bucket4, const int* __restrict__ ovf_cnt,
              const int* __restrict__ ovf, f4* __restrict__ out4, int N) {
    int l = threadIdx.x & 15;
    int ngrp = (gridDim.x * 256) >> 4;
    int novf = *ovf_cnt;                       // 0 in practice
    if (novf > OVF_CAP) novf = OVF_CAP;
    for (int gid = (blockIdx.x * 256 + threadIdx.x) >> 4; gid < N; gid += ngrp) {
        int deg = cursor[gid];
        if (deg > CAP) deg = CAP;
        const int4* row4 = bucket4 + gid * (CAP / 4);   // one 128B line
        f4 acc = {0.f, 0.f, 0.f, 0.f};
        int j = 0;
        for (; j + 3 < deg; j += 4) {
            int4 ea = row4[j >> 2];            // 16B broadcast load
            f4 a = mj4[(size_t)ea.x * 16 + l];
            f4 b = mj4[(size_t)ea.y * 16 + l];
            f4 c = mj4[(size_t)ea.z * 16 + l];
            f4 d = mj4[(size_t)ea.w * 16 + l];
            acc += (a + b) + (c + d);
        }
        if (j < deg) {
            int4 ea = row4[j >> 2];            // tail: 1-3 entries of this int4
            int e[4] = {ea.x, ea.y, ea.z, ea.w};
            for (int k = 0; j + k < deg; ++k)
                acc += mj4[(size_t)e[k] * 16 + l];
        }
        if (novf > 0) {                        // exact, expected never taken
            const int* row = (const int*)row4; (void)row;
            for (int k = 0; k < novf; ++k) {
                if (ovf[2 * k] == gid) acc += mj4[(size_t)ovf[2 * k + 1] * 16 + l];
            }
        }
        out4[(size_t)gid * 16 + l] = acc;
    }
}

extern "C" void kernel_launch(void* const* d_in, const int* in_sizes, int n_in,
                              void* d_out, int out_size, void* d_ws, size_t ws_size,
                              hipStream_t stream) {
    const float* mj = (const float*)d_in[0];
    const int* edge_index = (const int*)d_in[1];  // [2, E] int32 row-major
    int E = in_sizes[1] / 2;
    const int* tgt = edge_index + E;              // row 1 = targets
    int N = out_size / FEAT;                      // 100,000

    int* cursor  = (int*)d_ws;                    // N
    int* ovf_cnt = cursor + N;                    // 1 (+3 pad)
    int* ovf     = cursor + N + 4;                // 2*OVF_CAP, 16B-aligned
    int* bucket  = ovf + 2 * OVF_CAP;             // N*CAP, 16B-aligned

    hipMemsetAsync(cursor, 0, (size_t)(N + 4) * sizeof(int), stream);

    int eblk = (E + 511) / 512;
    scatter_kernel<<<eblk, 512, 0, stream>>>(tgt, cursor, bucket, ovf_cnt, ovf, E);

    int gblk = 2048;                              // grid-stride persistent gather
    gather_kernel<<<gblk, 256, 0, stream>>>(
        (const f4*)mj, cursor, (const int4*)bucket, ovf_cnt, ovf, (f4*)d_out, N);
}

// Round 10
// 121.476 us; speedup vs baseline: 1.0982x; 1.0982x over previous
//
#include <hip/hip_runtime.h>

// segment_sum via fixed-stride bucketing + gather, exact overflow fold.
// E = 1M edges, D = 64 f32 features, N = 100K nodes.
// R9: consolidation — exact resubmission of R7, the measured-best (122.1 us).
// R8's micros (int4 bucket loads + grid-stride gather + scatter@512) were
// collectively -11 us; reverted. Band across 9 rounds: 122-133 us; structure
// is bound by: 256MB random-row read (~4-4.5 TB/s granule ceiling) + 1M
// device atomics + memset/launch overhead.
// No NT hints (R3 lesson), no cooperative fusion (R6 lesson).
//
// ws ints: cursor[N] | ovf_cnt(+3 pad) | ovf[2*OVF_CAP] | bucket[N*CAP]

typedef float f4 __attribute__((ext_vector_type(4)));

#define FEAT 64
#define CAP 32            // one 128B line per node row (avg deg 10)
#define OVF_CAP (1 << 20)

__global__ void __launch_bounds__(256)
scatter_kernel(const int* __restrict__ tgt, int* __restrict__ cursor,
               int* __restrict__ bucket, int* __restrict__ ovf_cnt,
               int* __restrict__ ovf, int E) {
    int i = blockIdx.x * 256 + threadIdx.x;
    if (i >= E) return;
    int t = tgt[i];
    int pos = atomicAdd(&cursor[t], 1);
    if (pos < CAP) {
        bucket[t * CAP + pos] = i;    // plain store: L2 coalesces the region
    } else {                          // exact fallback, expected never
        int q = atomicAdd(ovf_cnt, 1);
        if (q < OVF_CAP) { ovf[2 * q] = t; ovf[2 * q + 1] = i; }
    }
}

// 16-lane group per node; lane = float4 slot; 4 rows in flight per group
__global__ void __launch_bounds__(256)
gather_kernel(const f4* __restrict__ mj4, const int* __restrict__ cursor,
              const int* __restrict__ bucket, const int* __restrict__ ovf_cnt,
              const int* __restrict__ ovf, f4* __restrict__ out4, int N) {
    int gid = (blockIdx.x * 256 + threadIdx.x) >> 4;
    int l = threadIdx.x & 15;
    if (gid >= N) return;
    int deg = cursor[gid];
    if (deg > CAP) deg = CAP;
    const int* row = bucket + gid * CAP;   // exactly one 128B line
    f4 acc = {0.f, 0.f, 0.f, 0.f};
    int j = 0;
    for (; j + 3 < deg; j += 4) {
        int e0 = row[j], e1 = row[j + 1], e2 = row[j + 2], e3 = row[j + 3];
        f4 a = mj4[(size_t)e0 * 16 + l];
        f4 b = mj4[(size_t)e1 * 16 + l];
        f4 c = mj4[(size_t)e2 * 16 + l];
        f4 d = mj4[(size_t)e3 * 16 + l];
        acc += (a + b) + (c + d);
    }
    for (; j < deg; ++j) {
        acc += mj4[(size_t)row[j] * 16 + l];
    }
    // exact overflow fold; novf==0 in practice -> one cached scalar load
    int novf = *ovf_cnt;
    if (novf > 0) {
        if (novf > OVF_CAP) novf = OVF_CAP;
        for (int k = 0; k < novf; ++k) {
            if (ovf[2 * k] == gid) acc += mj4[(size_t)ovf[2 * k + 1] * 16 + l];
        }
    }
    out4[(size_t)gid * 16 + l] = acc;
}

extern "C" void kernel_launch(void* const* d_in, const int* in_sizes, int n_in,
                              void* d_out, int out_size, void* d_ws, size_t ws_size,
                              hipStream_t stream) {
    const float* mj = (const float*)d_in[0];
    const int* edge_index = (const int*)d_in[1];  // [2, E] int32 row-major
    int E = in_sizes[1] / 2;
    const int* tgt = edge_index + E;              // row 1 = targets
    int N = out_size / FEAT;                      // 100,000

    int* cursor  = (int*)d_ws;                    // N
    int* ovf_cnt = cursor + N;                    // 1 (+3 pad)
    int* ovf     = cursor + N + 4;                // 2*OVF_CAP, 16B-aligned
    int* bucket  = ovf + 2 * OVF_CAP;             // N*CAP, 16B-aligned

    hipMemsetAsync(cursor, 0, (size_t)(N + 4) * sizeof(int), stream);

    int eblk = (E + 255) / 256;
    scatter_kernel<<<eblk, 256, 0, stream>>>(tgt, cursor, bucket, ovf_cnt, ovf, E);

    int gblk = (N * 16 + 255) / 256;
    gather_kernel<<<gblk, 256, 0, stream>>>(
        (const f4*)mj, cursor, bucket, ovf_cnt, ovf, (f4*)d_out, N);
}